// Round 3
// baseline (45.357 us; speedup 1.0000x reference)
//
#include <hip/hip_runtime.h>

#define N  256
#define NH 64
#define NC 14

// Kernel 1: one block per anchor i (256 threads, thread j owns column j).
// Computes per-i: Z_i (exact int64), numerator num_i = sum_{j,k} rij2 * relu(ds_ij - ds_ik + 5)
// over kept triplets (fp64), and count_i (exact int). Writes loss_i = num_i / Z_i.
__global__ __launch_bounds__(256) void osml_per_i(
    const float* __restrict__ H,   // hash_features [N][NH]
    const float* __restrict__ L,   // labels        [N][NC]
    double* __restrict__ loss_i,
    int*    __restrict__ cnt_i)
{
    const int i = blockIdx.x;
    const int j = threadIdx.x;

    __shared__ float  Hi[NH];
    __shared__ float  Li[NC];
    __shared__ double ds[N];   // dist_sim[i][*]
    __shared__ int    dg[N];   // dist_gt[i][*] (integer)
    __shared__ int    g2[N];   // 2^dist_gt[i][*]

    if (j < NH) Hi[j] = H[i * NH + j];
    if (j < NC) Li[j] = L[i * NC + j];
    __syncthreads();

    // dist_sim[i][j] = 0.5 * (NH - <H_i, H_j>)  in fp64
    double hh = 0.0;
    #pragma unroll
    for (int h = 0; h < NH; ++h)
        hh += (double)Hi[h] * (double)H[j * NH + h];
    ds[j] = 0.5 * ((double)NH - hh);

    // dist_gt[i][j] = <L_i, L_j> — exact small integer; diagonal zeroed
    float dsum = 0.0f;
    #pragma unroll
    for (int c = 0; c < NC; ++c)
        dsum += Li[c] * L[j * NC + c];
    int d = (int)(dsum + 0.5f);
    if (j == i) d = 0;
    dg[j] = d;
    g2[j] = 1 << d;
    __syncthreads();

    const int    dj  = dg[j];
    const int    g2j = g2[j];
    const double dsj = ds[j];

    long long Zp  = 0;    // exact
    double    num = 0.0;  // fp64 accumulation
    int       cnt = 0;    // exact

    for (int k = 0; k < N; ++k) {
        const int dk = dg[k];              // LDS broadcast (all lanes same k)
        if (dj > dk) {                     // mask
            const int r = g2j - g2[k];     // rij2, exact integer > 0
            Zp += r;
            if (dj - dk <= 2) {            // keep
                ++cnt;                     // counts includes keep regardless of relu
                const double t = dsj - ds[k] + 5.0;
                if (t > 0.0) num += (double)r * t;
            }
        }
    }

    // deterministic fixed-order block tree reduction
    __shared__ double    s_num[N];
    __shared__ long long s_z[N];
    __shared__ int       s_c[N];
    s_num[j] = num; s_z[j] = Zp; s_c[j] = cnt;
    __syncthreads();
    for (int off = N / 2; off > 0; off >>= 1) {
        if (j < off) {
            s_num[j] += s_num[j + off];
            s_z[j]   += s_z[j + off];
            s_c[j]   += s_c[j + off];
        }
        __syncthreads();
    }
    if (j == 0) {
        loss_i[i] = (s_z[0] > 0) ? (s_num[0] / (double)s_z[0]) : 0.0;
        cnt_i[i]  = s_c[0];
    }
}

// Kernel 2: single block — deterministic reduction over the 256 per-i results.
__global__ __launch_bounds__(256) void osml_final(
    const double* __restrict__ loss_i,
    const int*    __restrict__ cnt_i,
    float*        __restrict__ out)
{
    const int j = threadIdx.x;
    __shared__ double    s_l[N];
    __shared__ long long s_c[N];
    s_l[j] = loss_i[j];
    s_c[j] = (long long)cnt_i[j];
    __syncthreads();
    for (int off = N / 2; off > 0; off >>= 1) {
        if (j < off) {
            s_l[j] += s_l[j + off];
            s_c[j] += s_c[j + off];
        }
        __syncthreads();
    }
    if (j == 0) {
        const double    losses = s_l[0];
        const long long counts = s_c[0];
        out[0] = (float)((counts > 0) ? losses / (double)counts : losses);
    }
}

extern "C" void kernel_launch(void* const* d_in, const int* in_sizes, int n_in,
                              void* d_out, int out_size, void* d_ws, size_t ws_size,
                              hipStream_t stream) {
    const float* H = (const float*)d_in[0];  // hash_features [256][64] fp32
    const float* L = (const float*)d_in[1];  // labels        [256][14] fp32
    float* out = (float*)d_out;              // scalar fp32

    double* ws_loss = (double*)d_ws;           // 256 doubles
    int*    ws_cnt  = (int*)(ws_loss + N);     // 256 ints

    osml_per_i<<<N, N, 0, stream>>>(H, L, ws_loss, ws_cnt);
    osml_final<<<1, N, 0, stream>>>(ws_loss, ws_cnt, out);
}

// Round 4
// 27.258 us; speedup vs baseline: 1.6640x; 1.6640x over previous
//
#include <hip/hip_runtime.h>

#define N   256
#define NH  64
#define NC  14
#define NCH 8            // k-chunks per anchor i
#define KPC (N / NCH)    // 32 k's per chunk

// Kernel 1: block (i, ch) — thread j owns column j, loops over k in chunk ch.
// Emits partial (num fp64, Z int64, cnt int) per (i, ch). All integer sums are
// exact; fp64 partial-sum order is fixed -> deterministic across replays.
__global__ __launch_bounds__(256) void osml_partial(
    const float* __restrict__ H,    // hash_features [N][NH]
    const float* __restrict__ L,    // labels        [N][NC]
    double*    __restrict__ p_num,  // [N*NCH]
    long long* __restrict__ p_z,    // [N*NCH]
    int*       __restrict__ p_cnt)  // [N*NCH]
{
    const int i  = blockIdx.x;
    const int ch = blockIdx.y;
    const int j  = threadIdx.x;

    __shared__ float  Hi[NH];
    __shared__ float  Li[NC];
    __shared__ double ds[N];   // dist_sim[i][*]
    __shared__ int    dg[N];   // dist_gt[i][*]

    if (j < NH) Hi[j] = H[i * NH + j];
    if (j < NC) Li[j] = L[i * NC + j];
    __syncthreads();

    // dist_sim[i][j] in fp64; 4 accumulators, float4 global loads
    const float4* Hj4 = (const float4*)(H + j * NH);
    double a0 = 0.0, a1 = 0.0, a2 = 0.0, a3 = 0.0;
    #pragma unroll
    for (int q = 0; q < NH / 4; ++q) {
        float4 v = Hj4[q];
        a0 += (double)Hi[4 * q + 0] * (double)v.x;
        a1 += (double)Hi[4 * q + 1] * (double)v.y;
        a2 += (double)Hi[4 * q + 2] * (double)v.z;
        a3 += (double)Hi[4 * q + 3] * (double)v.w;
    }
    ds[j] = 0.5 * ((double)NH - ((a0 + a1) + (a2 + a3)));

    // dist_gt[i][j]: exact small integer, diagonal zeroed
    float dsum = 0.0f;
    #pragma unroll
    for (int c = 0; c < NC; ++c)
        dsum += Li[c] * L[j * NC + c];
    int d = (int)(dsum + 0.5f);
    if (j == i) d = 0;
    dg[j] = d;
    __syncthreads();

    const int    dj   = dg[j];
    const int    g2j  = 1 << dj;
    const double dsj5 = ds[j] + 5.0;

    long long Zp  = 0;
    int       cnt = 0;
    double    n0  = 0.0, n1 = 0.0;   // 2 accumulators break the fp64 FMA chain

    const int k0 = ch * KPC;
    #pragma unroll
    for (int kk = 0; kk < KPC; kk += 2) {
        {
            const int dk = dg[k0 + kk];          // LDS broadcast
            const int dd = dj - dk;
            const bool m = dd > 0;
            const int r  = m ? (g2j - (1 << dk)) : 0;   // exact rij2 (0 if masked)
            Zp += r;
            const bool keep = m & (dd <= 2);
            cnt += keep;
            const double t = dsj5 - ds[k0 + kk];
            const double w = (keep && t > 0.0) ? (double)r : 0.0;
            n0 = fma(w, t, n0);
        }
        {
            const int dk = dg[k0 + kk + 1];
            const int dd = dj - dk;
            const bool m = dd > 0;
            const int r  = m ? (g2j - (1 << dk)) : 0;
            Zp += r;
            const bool keep = m & (dd <= 2);
            cnt += keep;
            const double t = dsj5 - ds[k0 + kk + 1];
            const double w = (keep && t > 0.0) ? (double)r : 0.0;
            n1 = fma(w, t, n1);
        }
    }
    double num = n0 + n1;

    // wave-level fixed-order shuffle reduce (deterministic), then 4 waves -> LDS
    #pragma unroll
    for (int off = 32; off > 0; off >>= 1) {
        num += __shfl_down(num, off, 64);
        Zp  += __shfl_down(Zp,  off, 64);
        cnt += __shfl_down(cnt, off, 64);
    }
    __shared__ double    w_num[4];
    __shared__ long long w_z[4];
    __shared__ int       w_c[4];
    const int wid  = j >> 6;
    const int lane = j & 63;
    if (lane == 0) { w_num[wid] = num; w_z[wid] = Zp; w_c[wid] = cnt; }
    __syncthreads();
    if (j == 0) {
        const int o = i * NCH + ch;
        p_num[o] = ((w_num[0] + w_num[1]) + (w_num[2] + w_num[3]));
        p_z[o]   = w_z[0] + w_z[1] + w_z[2] + w_z[3];
        p_cnt[o] = w_c[0] + w_c[1] + w_c[2] + w_c[3];
    }
}

// Kernel 2: thread i folds its 8 chunks (fixed order), computes loss_i = num_i/Z_i,
// then a deterministic tree reduction over the 256 anchors.
__global__ __launch_bounds__(256) void osml_final(
    const double*    __restrict__ p_num,
    const long long* __restrict__ p_z,
    const int*       __restrict__ p_cnt,
    float*           __restrict__ out)
{
    const int j = threadIdx.x;

    double    num = 0.0;
    long long Z   = 0;
    long long cnt = 0;
    #pragma unroll
    for (int ch = 0; ch < NCH; ++ch) {
        const int o = j * NCH + ch;
        num += p_num[o];
        Z   += p_z[o];
        cnt += p_cnt[o];
    }
    const double loss = (Z > 0) ? (num / (double)Z) : 0.0;

    __shared__ double    s_l[N];
    __shared__ long long s_c[N];
    s_l[j] = loss;
    s_c[j] = cnt;
    __syncthreads();
    for (int off = N / 2; off > 0; off >>= 1) {
        if (j < off) {
            s_l[j] += s_l[j + off];
            s_c[j] += s_c[j + off];
        }
        __syncthreads();
    }
    if (j == 0) {
        const double    losses = s_l[0];
        const long long counts = s_c[0];
        out[0] = (float)((counts > 0) ? losses / (double)counts : losses);
    }
}

extern "C" void kernel_launch(void* const* d_in, const int* in_sizes, int n_in,
                              void* d_out, int out_size, void* d_ws, size_t ws_size,
                              hipStream_t stream) {
    const float* H = (const float*)d_in[0];  // hash_features [256][64] fp32
    const float* L = (const float*)d_in[1];  // labels        [256][14] fp32
    float* out = (float*)d_out;              // scalar fp32

    double*    p_num = (double*)d_ws;                  // 2048 doubles
    long long* p_z   = (long long*)(p_num + N * NCH);  // 2048 int64
    int*       p_cnt = (int*)(p_z + N * NCH);          // 2048 int32

    osml_partial<<<dim3(N, NCH), 256, 0, stream>>>(H, L, p_num, p_z, p_cnt);
    osml_final<<<1, 256, 0, stream>>>(p_num, p_z, p_cnt, out);
}